// Round 2
// baseline (544.145 us; speedup 1.0000x reference)
//
#include <hip/hip_runtime.h>

// MHA with sigmoid attention. Interface dtypes: float32 in / float32 out
// (per reference). Internally: f16 MFMA (same rate as bf16, 8x finer mantissa),
// f32 accumulate. B=4, S=2048, D=1024, H=16, Dh=64.
// Pipeline: Q/K/V projections -> sigmoid attention -> out projection.

typedef _Float16 f16x8 __attribute__((ext_vector_type(8)));
typedef float    f32x4 __attribute__((ext_vector_type(4)));

#define BM 128
#define BN 128
#define BK 32
#define LDK 40  // f16 row stride 80B: 16B-aligned chunks, 2-way bank aliasing = free (m136)

struct Frag16 { f16x8 lo, hi; };

// Load 16 contiguous elements, converting f32->f16 if needed. Pure register op
// (safe to call BEFORE the barrier; the LDS store happens after).
template <typename AT>
__device__ inline Frag16 load16(const AT* p) {
  Frag16 r;
  if constexpr (sizeof(AT) == 4) {
    float4 a = *(const float4*)p,     b = *(const float4*)(p + 4);
    float4 c = *(const float4*)(p + 8), d = *(const float4*)(p + 12);
    r.lo = (f16x8){(_Float16)a.x, (_Float16)a.y, (_Float16)a.z, (_Float16)a.w,
                   (_Float16)b.x, (_Float16)b.y, (_Float16)b.z, (_Float16)b.w};
    r.hi = (f16x8){(_Float16)c.x, (_Float16)c.y, (_Float16)c.z, (_Float16)c.w,
                   (_Float16)d.x, (_Float16)d.y, (_Float16)d.z, (_Float16)d.w};
  } else {
    r.lo = *(const f16x8*)p;
    r.hi = *(const f16x8*)(p + 8);
  }
  return r;
}

// Y[M,N] = A[M,K] @ W[N,K]^T + bias[N]
template <typename AT, typename OT>
__global__ __launch_bounds__(256) void gemm_bt(const AT* __restrict__ A,
                                               const float* __restrict__ W,
                                               const float* __restrict__ bias,
                                               OT* __restrict__ Y,
                                               int M, int N, int K) {
  __shared__ __align__(16) _Float16 sA[BM * LDK];
  __shared__ __align__(16) _Float16 sB[BN * LDK];

  const int t = threadIdx.x;
  const int lane = t & 63, wid = t >> 6;
  const int m0 = blockIdx.x * BM, n0 = blockIdx.y * BN;
  const int wm = (wid >> 1) * 64, wn = (wid & 1) * 64;

  f32x4 acc[4][4] = {};

  // staging: each thread covers 16 elements: row = t>>1 (0..127), col = (t&1)*16
  const int srow = t >> 1, scol = (t & 1) * 16;
  const AT*    pA = A + (size_t)(m0 + srow) * K + scol;
  const float* pW = W + (size_t)(n0 + srow) * K + scol;
  _Float16* dA = &sA[srow * LDK + scol];
  _Float16* dB = &sB[srow * LDK + scol];

  const int lrow = lane & 15, lk = (lane >> 4) * 8;

  for (int k0 = 0; k0 < K; k0 += BK) {
    Frag16 fa = load16(pA + k0);
    Frag16 fb = load16(pW + k0);
    __syncthreads();  // previous iteration's LDS reads must finish before overwrite
    *(f16x8*)(dA)     = fa.lo;
    *(f16x8*)(dA + 8) = fa.hi;
    *(f16x8*)(dB)     = fb.lo;
    *(f16x8*)(dB + 8) = fb.hi;
    __syncthreads();

    f16x8 af[4], bfr[4];
#pragma unroll
    for (int i = 0; i < 4; i++)
      af[i] = *(const f16x8*)&sA[(wm + i * 16 + lrow) * LDK + lk];
#pragma unroll
    for (int j = 0; j < 4; j++)
      bfr[j] = *(const f16x8*)&sB[(wn + j * 16 + lrow) * LDK + lk];
#pragma unroll
    for (int i = 0; i < 4; i++)
#pragma unroll
      for (int j = 0; j < 4; j++)
        acc[i][j] = __builtin_amdgcn_mfma_f32_16x16x32_f16(af[i], bfr[j], acc[i][j], 0, 0, 0);
  }

  // epilogue: C/D layout col=lane&15, row=(lane>>4)*4+r (m89-verified)
  const int orow = (lane >> 4) * 4, ocol = lane & 15;
#pragma unroll
  for (int j = 0; j < 4; j++) {
    const int col = n0 + wn + j * 16 + ocol;
    const float bv = bias[col];
#pragma unroll
    for (int i = 0; i < 4; i++) {
#pragma unroll
      for (int r = 0; r < 4; r++) {
        const int row = m0 + wm + i * 16 + orow + r;
        Y[(size_t)row * N + col] = (OT)(acc[i][j][r] + bv);
      }
    }
  }
}

// ---------------- attention: O = sigmoid(Q K^T / 8) V, per (b,h), f16 in/out ----
#define LDA 72  // 144B row stride: 16B-aligned, 2-way banks

__global__ __launch_bounds__(256) void attn_sig(const _Float16* __restrict__ Q,
                                                const _Float16* __restrict__ K,
                                                const _Float16* __restrict__ V,
                                                _Float16* __restrict__ O) {
  __shared__ __align__(16) _Float16 sK[64 * LDA];     // [key][dh]
  __shared__ __align__(16) _Float16 sV[64 * LDA];     // transposed: [dh][key]
  __shared__ __align__(16) _Float16 sP[4][16 * LDA];  // per-wave P tile [q][key]

  const int t = threadIdx.x, lane = t & 63, wid = t >> 6;
  const int b = blockIdx.z, h = blockIdx.y, q0 = blockIdx.x * 64;
  const int S = 2048, D = 1024;
  const size_t base = ((size_t)b * S) * D + h * 64;

  const int lrow = lane & 15, lk = (lane >> 4) * 8;

  // Q fragments for this wave's 16 q-rows; dh split into two k-steps of 32
  f16x8 qf[2];
  {
    const _Float16* qp = Q + base + (size_t)(q0 + wid * 16 + lrow) * D;
    qf[0] = *(const f16x8*)(qp + 0 + lk);
    qf[1] = *(const f16x8*)(qp + 32 + lk);
  }

  f32x4 oacc[4] = {};
  const int srow = t >> 2, scol = (t & 3) * 16;  // staging: 4 threads/row, 16 f16 each
  const float sc = 0.125f;                       // 1/sqrt(64)

  for (int kt = 0; kt < S; kt += 64) {
    const _Float16* kp = K + base + (size_t)(kt + srow) * D + scol;
    uint4 k0 = *(const uint4*)kp;
    uint4 k1 = *(const uint4*)(kp + 8);
    const _Float16* vp = V + base + (size_t)(kt + srow) * D + scol;
    uint4 v0 = *(const uint4*)vp;
    uint4 v1 = *(const uint4*)(vp + 8);
    __syncthreads();  // previous iteration's LDS reads done
    *(uint4*)&sK[srow * LDA + scol]     = k0;
    *(uint4*)&sK[srow * LDA + scol + 8] = k1;
    {  // transpose V into sV[dh][key]
      union { uint4 u; _Float16 e[8]; } c0, c1;
      c0.u = v0; c1.u = v1;
#pragma unroll
      for (int i = 0; i < 8; i++) {
        sV[(scol + i) * LDA + srow]     = c0.e[i];
        sV[(scol + 8 + i) * LDA + srow] = c1.e[i];
      }
    }
    __syncthreads();

    // scores: S[q][key] over dh (2 MFMA k-steps)
    f32x4 sacc[4] = {};
#pragma unroll
    for (int j = 0; j < 4; j++) {
      f16x8 kf0 = *(const f16x8*)&sK[(j * 16 + lrow) * LDA + lk];
      f16x8 kf1 = *(const f16x8*)&sK[(j * 16 + lrow) * LDA + 32 + lk];
      sacc[j] = __builtin_amdgcn_mfma_f32_16x16x32_f16(qf[0], kf0, sacc[j], 0, 0, 0);
      sacc[j] = __builtin_amdgcn_mfma_f32_16x16x32_f16(qf[1], kf1, sacc[j], 0, 0, 0);
    }

    // sigmoid -> P (f16) via LDS (C-layout -> A-layout transform, m120 pattern)
    const int prow = (lane >> 4) * 4;
#pragma unroll
    for (int j = 0; j < 4; j++)
#pragma unroll
      for (int r = 0; r < 4; r++) {
        const float p = 1.0f / (1.0f + __expf(-sacc[j][r] * sc));
        sP[wid][(prow + r) * LDA + j * 16 + lrow] = (_Float16)p;
      }
    __syncthreads();  // P visible; sV writes ordered vs reads

    // PV: O[q][d] += P[q][key] V[key][d]
#pragma unroll
    for (int kk = 0; kk < 2; kk++) {
      f16x8 pf = *(const f16x8*)&sP[wid][lrow * LDA + kk * 32 + lk];
#pragma unroll
      for (int j = 0; j < 4; j++) {
        f16x8 vf = *(const f16x8*)&sV[(j * 16 + lrow) * LDA + kk * 32 + lk];
        oacc[j] = __builtin_amdgcn_mfma_f32_16x16x32_f16(pf, vf, oacc[j], 0, 0, 0);
      }
    }
  }

  // epilogue
  const int orow = (lane >> 4) * 4, ocol = lane & 15;
#pragma unroll
  for (int j = 0; j < 4; j++)
#pragma unroll
    for (int r = 0; r < 4; r++) {
      const size_t row = q0 + wid * 16 + orow + r;
      O[base + row * D + j * 16 + ocol] = (_Float16)oacc[j][r];
    }
}

extern "C" void kernel_launch(void* const* d_in, const int* in_sizes, int n_in,
                              void* d_out, int out_size, void* d_ws, size_t ws_size,
                              hipStream_t stream) {
  const float* query = (const float*)d_in[0];
  const float* key   = (const float*)d_in[1];
  const float* value = (const float*)d_in[2];
  const float* Wq = (const float*)d_in[3];
  const float* bq = (const float*)d_in[4];
  const float* Wk = (const float*)d_in[5];
  const float* bk = (const float*)d_in[6];
  const float* Wv = (const float*)d_in[7];
  const float* bv = (const float*)d_in[8];
  const float* Wo = (const float*)d_in[9];
  const float* bo = (const float*)d_in[10];
  float* out = (float*)d_out;

  const int Bb = 4, S = 2048, D = 1024, M = Bb * S;
  _Float16* Qp = (_Float16*)d_ws;
  _Float16* Kp = Qp + (size_t)M * D;
  _Float16* Vp = Kp + (size_t)M * D;
  _Float16* AO = Vp + (size_t)M * D;

  dim3 gg(M / BM, D / BN), bb(256);
  gemm_bt<float, _Float16><<<gg, bb, 0, stream>>>(query, Wq, bq, Qp, M, D, D);
  gemm_bt<float, _Float16><<<gg, bb, 0, stream>>>(key,   Wk, bk, Kp, M, D, D);
  gemm_bt<float, _Float16><<<gg, bb, 0, stream>>>(value, Wv, bv, Vp, M, D, D);
  attn_sig<<<dim3(S / 64, 16, Bb), bb, 0, stream>>>(Qp, Kp, Vp, AO);
  gemm_bt<_Float16, float><<<gg, bb, 0, stream>>>(AO, Wo, bo, out, M, D, D);
}

// Round 3
// 388.534 us; speedup vs baseline: 1.4005x; 1.4005x over previous
//
#include <hip/hip_runtime.h>

// MHA sigmoid-attention, f32 interface, f16 MFMA internals.
// B=4, S=2048, D=1024, H=16, Dh=64.
// R3: V^T materialized by the V-projection GEMM (no LDS transpose),
//     S^T-orientation QK^T -> packed-8B P writes (no scalar LDS),
//     global_load_lds(16B) staging with XOR-swizzled LDS in the GEMMs.

typedef _Float16 f16x4 __attribute__((ext_vector_type(4)));
typedef _Float16 f16x8 __attribute__((ext_vector_type(8)));
typedef float    f32x4 __attribute__((ext_vector_type(4)));

typedef __attribute__((address_space(3))) void* lds_vp;
typedef const __attribute__((address_space(1))) void* gbl_vp;

__device__ __forceinline__ void gld_lds16(const void* g, void* l) {
  __builtin_amdgcn_global_load_lds((gbl_vp)g, (lds_vp)l, 16, 0, 0);
}

__device__ __forceinline__ f16x8 cvt8(float4 a, float4 b) {
  return (f16x8){(_Float16)a.x, (_Float16)a.y, (_Float16)a.z, (_Float16)a.w,
                 (_Float16)b.x, (_Float16)b.y, (_Float16)b.z, (_Float16)b.w};
}

#define BM 128
#define BN 128
#define BK 32

// LDS tile: unpadded [128 rows][32 f16], 16B chunks XOR-swizzled:
// global 16B-quad q of row r lives at chunk r*4 + (q ^ ((r>>1)&3)).
// Fragment b128 reads then hit all 8 bank-quads over 8 rows -> 2-way (free).
// global_load_lds: wave w, lane l -> chunk 64w+l; row=16w+(l>>2);
// global quad = (l&3) ^ ((l>>3)&3)  (w-independent since 8w%4==0).

template <bool AF16, bool BF16, bool TRANSV, bool OUTF32>
__global__ __launch_bounds__(256) void gemm_bt(const void* __restrict__ Av,
                                               const void* __restrict__ Bv,
                                               const float* __restrict__ bias,
                                               void* __restrict__ Yv,
                                               int M, int N, int K) {
  __shared__ __align__(16) _Float16 sA[BM * BK];
  __shared__ __align__(16) _Float16 sB[BN * BK];

  const int t = threadIdx.x, lane = t & 63, wid = t >> 6;
  const int m0 = blockIdx.x * BM, n0 = blockIdx.y * BN;
  const int wm = (wid >> 1) * 64, wn = (wid & 1) * 64;
  const int lrow = lane & 15, g = lane >> 4;

  f32x4 acc[4][4] = {};

  // async staging geometry
  const int arow = 16 * wid + (lane >> 2);
  const int gq = (lane & 3) ^ ((lane >> 3) & 3);
  _Float16* lA1 = sA + wid * 512;          // chunks 64w..64w+63 (rows 0..63)
  _Float16* lA2 = sA + 2048 + wid * 512;   // rows 64..127
  _Float16* lB1 = sB + wid * 512;
  _Float16* lB2 = sB + 2048 + wid * 512;

  // manual (f32-convert) staging geometry
  const int mrow = t >> 1, mhalf = t & 1;
  const int mm = (mrow >> 1) & 3;
  const int ch_lo = mrow * 4 + ((2 * mhalf) ^ mm);
  const int ch_hi = ch_lo ^ 1;

  const _Float16* pA16a = nullptr; const _Float16* pA16b = nullptr;
  const float* pA32 = nullptr;
  if constexpr (AF16) {
    const _Float16* A = (const _Float16*)Av;
    pA16a = A + (size_t)(m0 + arow) * K + gq * 8;
    pA16b = A + (size_t)(m0 + 64 + arow) * K + gq * 8;
  } else {
    pA32 = (const float*)Av + (size_t)(m0 + mrow) * K + mhalf * 16;
  }
  const _Float16* pB16a = nullptr; const _Float16* pB16b = nullptr;
  const float* pB32 = nullptr;
  if constexpr (BF16) {
    const _Float16* B = (const _Float16*)Bv;
    pB16a = B + (size_t)(n0 + arow) * K + gq * 8;
    pB16b = B + (size_t)(n0 + 64 + arow) * K + gq * 8;
  } else {
    pB32 = (const float*)Bv + (size_t)(n0 + mrow) * K + mhalf * 16;
  }

  const int xr = g ^ ((lrow >> 1) & 3);  // lane-constant fragment swizzle

  for (int k0 = 0; k0 < K; k0 += BK) {
    float4 av[4], bv4[4];
    if constexpr (!AF16) {
      const float4* p = (const float4*)(pA32 + k0);
      av[0] = p[0]; av[1] = p[1]; av[2] = p[2]; av[3] = p[3];
    }
    if constexpr (!BF16) {
      const float4* p = (const float4*)(pB32 + k0);
      bv4[0] = p[0]; bv4[1] = p[1]; bv4[2] = p[2]; bv4[3] = p[3];
    }
    __syncthreads();  // all reads of prev tile done
    if constexpr (AF16) {
      gld_lds16(pA16a + k0, lA1);
      gld_lds16(pA16b + k0, lA2);
    } else {
      *(f16x8*)(sA + ch_lo * 8) = cvt8(av[0], av[1]);
      *(f16x8*)(sA + ch_hi * 8) = cvt8(av[2], av[3]);
    }
    if constexpr (BF16) {
      gld_lds16(pB16a + k0, lB1);
      gld_lds16(pB16b + k0, lB2);
    } else {
      *(f16x8*)(sB + ch_lo * 8) = cvt8(bv4[0], bv4[1]);
      *(f16x8*)(sB + ch_hi * 8) = cvt8(bv4[2], bv4[3]);
    }
    __syncthreads();  // compiler drains vmcnt(0)+lgkmcnt here (m97 pattern)

    f16x8 af[4], bf[4];
#pragma unroll
    for (int i = 0; i < 4; i++)
      af[i] = *(const f16x8*)(sA + (wm + i * 16 + lrow) * 32 + xr * 8);
#pragma unroll
    for (int j = 0; j < 4; j++)
      bf[j] = *(const f16x8*)(sB + (wn + j * 16 + lrow) * 32 + xr * 8);
#pragma unroll
    for (int i = 0; i < 4; i++)
#pragma unroll
      for (int j = 0; j < 4; j++)
        acc[i][j] = __builtin_amdgcn_mfma_f32_16x16x32_f16(af[i], bf[j], acc[i][j], 0, 0, 0);
  }

  // epilogue: C/D layout col=lane&15, row=(lane>>4)*4+r (m89-verified)
  const int orow = g * 4, ocol = lrow;
#pragma unroll
  for (int j = 0; j < 4; j++) {
    const int col = n0 + wn + j * 16 + ocol;
    const float bv = bias[col];
#pragma unroll
    for (int i = 0; i < 4; i++) {
      const int row = m0 + wm + i * 16 + orow;
      if constexpr (TRANSV) {
        // write V^T: [b][h][dh][s], b=row>>11, s=row&2047, h=col>>6, dh=col&63
        _Float16* VT = (_Float16*)Yv;
        _Float16* dst = VT + (((size_t)(row >> 11) * 16 + (col >> 6)) * 64 + (col & 63)) * 2048 +
                        (row & 2047);
        f16x4 v = {(_Float16)(acc[i][j][0] + bv), (_Float16)(acc[i][j][1] + bv),
                   (_Float16)(acc[i][j][2] + bv), (_Float16)(acc[i][j][3] + bv)};
        *(f16x4*)dst = v;  // 4 consecutive s -> aligned 8B store
      } else if constexpr (OUTF32) {
        float* Y = (float*)Yv;
#pragma unroll
        for (int r = 0; r < 4; r++) Y[(size_t)(row + r) * N + col] = acc[i][j][r] + bv;
      } else {
        _Float16* Y = (_Float16*)Yv;
#pragma unroll
        for (int r = 0; r < 4; r++) Y[(size_t)(row + r) * N + col] = (_Float16)(acc[i][j][r] + bv);
      }
    }
  }
}

// ---------------- attention: O = sigmoid(Q K^T / 8) V ----------------
// 128 q/block, 4 waves, 32 q/wave (2 groups of 16). S^T orientation QK^T.
#define LDA 72  // 144B row stride; frag reads/writes land at minimum bank cycles

__global__ __launch_bounds__(256, 4) void attn_sig(const _Float16* __restrict__ Q,
                                                   const _Float16* __restrict__ K,
                                                   const _Float16* __restrict__ VT,
                                                   _Float16* __restrict__ O) {
  __shared__ __align__(16) _Float16 sK[64 * LDA];      // [key][dh]
  __shared__ __align__(16) _Float16 sVT[64 * LDA];     // [dh][key] (from global V^T)
  __shared__ __align__(16) _Float16 sP[4][32 * LDA];   // per-wave P [q_local][key]

  const int t = threadIdx.x, lane = t & 63, wid = t >> 6;
  const int b = blockIdx.z, h = blockIdx.y, q0 = blockIdx.x * 128;
  const int lrow = lane & 15, g = lane >> 4;
  const int qw = q0 + wid * 32;  // wave's 32 q rows

  // Q fragments (serve as MFMA B-operand in the swapped QK^T: same data layout)
  f16x8 qf[2][2];
#pragma unroll
  for (int gr = 0; gr < 2; gr++) {
    const _Float16* qp = Q + (size_t)(b * 2048 + qw + gr * 16 + lrow) * 1024 + h * 64;
    qf[gr][0] = *(const f16x8*)(qp + g * 8);
    qf[gr][1] = *(const f16x8*)(qp + 32 + g * 8);
  }

  f32x4 oacc[2][4] = {};
  const int srow = t >> 2, scol = (t & 3) * 16;  // staging: 4 threads/row, 32B each
  const _Float16* vtb = VT + ((size_t)(b * 16 + h) * 64 + srow) * 2048;

  for (int kt = 0; kt < 2048; kt += 64) {
    const _Float16* kp = K + (size_t)(b * 2048 + kt + srow) * 1024 + h * 64 + scol;
    uint4 ka = *(const uint4*)kp, kb = *(const uint4*)(kp + 8);
    const _Float16* vp = vtb + kt + scol;
    uint4 va = *(const uint4*)vp, vb = *(const uint4*)(vp + 8);
    __syncthreads();  // prev tile's reads done
    *(uint4*)&sK[srow * LDA + scol] = ka;
    *(uint4*)&sK[srow * LDA + scol + 8] = kb;
    *(uint4*)&sVT[srow * LDA + scol] = va;
    *(uint4*)&sVT[srow * LDA + scol + 8] = vb;
    __syncthreads();

    // QK^T in S^T orientation: mfma(A=K, B=Q) -> D[key][q]
#pragma unroll
    for (int gr = 0; gr < 2; gr++) {
      f32x4 sacc[4] = {};
#pragma unroll
      for (int j = 0; j < 4; j++) {
        f16x8 kf0 = *(const f16x8*)&sK[(j * 16 + lrow) * LDA + g * 8];
        f16x8 kf1 = *(const f16x8*)&sK[(j * 16 + lrow) * LDA + 32 + g * 8];
        sacc[j] = __builtin_amdgcn_mfma_f32_16x16x32_f16(kf0, qf[gr][0], sacc[j], 0, 0, 0);
        sacc[j] = __builtin_amdgcn_mfma_f32_16x16x32_f16(kf1, qf[gr][1], sacc[j], 0, 0, 0);
      }
      // sigmoid; C-layout rows are 4 consecutive KEYS -> one packed 8B write per j
#pragma unroll
      for (int j = 0; j < 4; j++) {
        f16x4 p4;
#pragma unroll
        for (int r = 0; r < 4; r++) {
          float e = __expf(sacc[j][r] * -0.125f);
          p4[r] = (_Float16)__builtin_amdgcn_rcpf(1.0f + e);
        }
        // P[q_local = gr*16 + (lane&15)][key = j*16 + 4g + r]
        *(f16x4*)&sP[wid][(gr * 16 + lrow) * LDA + j * 16 + g * 4] = p4;
      }
    }
    // PV: O[q][dh] += P[q][key] VT[dh][key]; same-wave sP RAW -> lgkmcnt only
#pragma unroll
    for (int kk = 0; kk < 2; kk++) {
      f16x8 pf0 = *(const f16x8*)&sP[wid][(lrow) * LDA + kk * 32 + g * 8];
      f16x8 pf1 = *(const f16x8*)&sP[wid][(16 + lrow) * LDA + kk * 32 + g * 8];
#pragma unroll
      for (int j = 0; j < 4; j++) {
        f16x8 vf = *(const f16x8*)&sVT[(j * 16 + lrow) * LDA + kk * 32 + g * 8];
        oacc[0][j] = __builtin_amdgcn_mfma_f32_16x16x32_f16(pf0, vf, oacc[0][j], 0, 0, 0);
        oacc[1][j] = __builtin_amdgcn_mfma_f32_16x16x32_f16(pf1, vf, oacc[1][j], 0, 0, 0);
      }
    }
  }

  // epilogue: D[q][dh], col=dh=lane&15, row=q_local=4g+r
#pragma unroll
  for (int gr = 0; gr < 2; gr++)
#pragma unroll
    for (int j = 0; j < 4; j++)
#pragma unroll
      for (int r = 0; r < 4; r++)
        O[(size_t)(b * 2048 + qw + gr * 16 + g * 4 + r) * 1024 + h * 64 + j * 16 + lrow] =
            (_Float16)oacc[gr][j][r];
}

// ---------------- f32 -> f16 batch convert ----------------
struct CvtArgs {
  const float* src[7];
  _Float16* dst[7];
  int n[7];
  int cnt;
};

__global__ __launch_bounds__(256) void cvt_f32_f16(CvtArgs a) {
  const int ti = blockIdx.y;
  if (ti >= a.cnt) return;
  const int i = (blockIdx.x * 256 + threadIdx.x) * 8;
  if (i >= a.n[ti]) return;
  const float4* s = (const float4*)(a.src[ti] + i);
  float4 x = s[0], y = s[1];
  *(f16x8*)(a.dst[ti] + i) = cvt8(x, y);
}

extern "C" void kernel_launch(void* const* d_in, const int* in_sizes, int n_in,
                              void* d_out, int out_size, void* d_ws, size_t ws_size,
                              hipStream_t stream) {
  const float* query = (const float*)d_in[0];
  const float* key   = (const float*)d_in[1];
  const float* value = (const float*)d_in[2];
  const float* Wq = (const float*)d_in[3];
  const float* bq = (const float*)d_in[4];
  const float* Wk = (const float*)d_in[5];
  const float* bk = (const float*)d_in[6];
  const float* Wv = (const float*)d_in[7];
  const float* bv = (const float*)d_in[8];
  const float* Wo = (const float*)d_in[9];
  const float* bo = (const float*)d_in[10];
  float* out = (float*)d_out;

  const int D = 1024, M = 8192;
  const size_t MB = 1024 * 1024;
  char* ws = (char*)d_ws;
  dim3 bb(256), gg(M / BM, D / BN), ga(16, 16, 4);

  if (ws_size >= 104 * MB) {
    _Float16* Xq = (_Float16*)(ws + 0 * MB);
    _Float16* Xk = (_Float16*)(ws + 16 * MB);
    _Float16* Xv = (_Float16*)(ws + 32 * MB);
    _Float16* Qp = (_Float16*)(ws + 48 * MB);
    _Float16* Kp = (_Float16*)(ws + 64 * MB);
    _Float16* VT = (_Float16*)(ws + 80 * MB);
    _Float16* Wf = (_Float16*)(ws + 96 * MB);  // 4 x 1M f16
    _Float16* AO = Xq;                         // Xq dead after Q-projection
    CvtArgs ca{};
    ca.src[0] = query; ca.dst[0] = Xq; ca.n[0] = M * D;
    ca.src[1] = key;   ca.dst[1] = Xk; ca.n[1] = M * D;
    ca.src[2] = value; ca.dst[2] = Xv; ca.n[2] = M * D;
    ca.src[3] = Wq; ca.dst[3] = Wf + 0 * 1048576; ca.n[3] = D * D;
    ca.src[4] = Wk; ca.dst[4] = Wf + 1 * 1048576; ca.n[4] = D * D;
    ca.src[5] = Wv; ca.dst[5] = Wf + 2 * 1048576; ca.n[5] = D * D;
    ca.src[6] = Wo; ca.dst[6] = Wf + 3 * 1048576; ca.n[6] = D * D;
    ca.cnt = 7;
    cvt_f32_f16<<<dim3(4096, 7), bb, 0, stream>>>(ca);
    gemm_bt<true, true, false, false><<<gg, bb, 0, stream>>>(Xq, Wf + 0 * 1048576, bq, Qp, M, D, D);
    gemm_bt<true, true, false, false><<<gg, bb, 0, stream>>>(Xk, Wf + 1 * 1048576, bk, Kp, M, D, D);
    gemm_bt<true, true, true,  false><<<gg, bb, 0, stream>>>(Xv, Wf + 2 * 1048576, bv, VT, M, D, D);
    attn_sig<<<ga, bb, 0, stream>>>(Qp, Kp, VT, AO);
    gemm_bt<true, true, false, true><<<gg, bb, 0, stream>>>(AO, Wf + 3 * 1048576, bo, out, M, D, D);
  } else if (ws_size >= 72 * MB) {
    _Float16* Wf = (_Float16*)(ws + 0 * MB);
    _Float16* Qp = (_Float16*)(ws + 8 * MB);
    _Float16* Kp = (_Float16*)(ws + 24 * MB);
    _Float16* VT = (_Float16*)(ws + 40 * MB);
    _Float16* AO = (_Float16*)(ws + 56 * MB);
    CvtArgs ca{};
    ca.src[0] = Wq; ca.dst[0] = Wf + 0 * 1048576; ca.n[0] = D * D;
    ca.src[1] = Wk; ca.dst[1] = Wf + 1 * 1048576; ca.n[1] = D * D;
    ca.src[2] = Wv; ca.dst[2] = Wf + 2 * 1048576; ca.n[2] = D * D;
    ca.src[3] = Wo; ca.dst[3] = Wf + 3 * 1048576; ca.n[3] = D * D;
    ca.cnt = 4;
    cvt_f32_f16<<<dim3(512, 4), bb, 0, stream>>>(ca);
    gemm_bt<false, true, false, false><<<gg, bb, 0, stream>>>(query, Wf + 0 * 1048576, bq, Qp, M, D, D);
    gemm_bt<false, true, false, false><<<gg, bb, 0, stream>>>(key,   Wf + 1 * 1048576, bk, Kp, M, D, D);
    gemm_bt<false, true, true,  false><<<gg, bb, 0, stream>>>(value, Wf + 2 * 1048576, bv, VT, M, D, D);
    attn_sig<<<ga, bb, 0, stream>>>(Qp, Kp, VT, AO);
    gemm_bt<true, true, false, true><<<gg, bb, 0, stream>>>(AO, Wf + 3 * 1048576, bo, out, M, D, D);
  } else {
    _Float16* Qp = (_Float16*)(ws + 0 * MB);
    _Float16* Kp = (_Float16*)(ws + 16 * MB);
    _Float16* VT = (_Float16*)(ws + 32 * MB);
    _Float16* AO = (_Float16*)(ws + 48 * MB);
    gemm_bt<false, false, false, false><<<gg, bb, 0, stream>>>(query, Wq, bq, Qp, M, D, D);
    gemm_bt<false, false, false, false><<<gg, bb, 0, stream>>>(key,   Wk, bk, Kp, M, D, D);
    gemm_bt<false, false, true,  false><<<gg, bb, 0, stream>>>(value, Wv, bv, VT, M, D, D);
    attn_sig<<<ga, bb, 0, stream>>>(Qp, Kp, VT, AO);
    gemm_bt<true, false, false, true><<<gg, bb, 0, stream>>>(AO, Wo, bo, out, M, D, D);
  }
}

// Round 4
// 379.471 us; speedup vs baseline: 1.4340x; 1.0239x over previous
//
#include <hip/hip_runtime.h>

// MHA sigmoid-attention, f32 interface, f16 MFMA internals.
// B=4, S=2048, D=1024, H=16, Dh=64.
// R4: fused QKV projection GEMM (N=3072, 6 blocks/CU);
//     attention P kept in registers via 32x32x16 (S^T) -> 32x32x8 (PV) layout
//     chain; V^T stored with s-bits 2<->3 swapped so PV A-frags are b128.

typedef _Float16 f16x4 __attribute__((ext_vector_type(4)));
typedef _Float16 f16x8 __attribute__((ext_vector_type(8)));
typedef float    f32x4 __attribute__((ext_vector_type(4)));
typedef float    f32x16 __attribute__((ext_vector_type(16)));

typedef __attribute__((address_space(3))) void* lds_vp;
typedef const __attribute__((address_space(1))) void* gbl_vp;

__device__ __forceinline__ void gld_lds16(const void* g, void* l) {
  __builtin_amdgcn_global_load_lds((gbl_vp)g, (lds_vp)l, 16, 0, 0);
}

__device__ __forceinline__ f16x8 cvt8(float4 a, float4 b) {
  return (f16x8){(_Float16)a.x, (_Float16)a.y, (_Float16)a.z, (_Float16)a.w,
                 (_Float16)b.x, (_Float16)b.y, (_Float16)b.z, (_Float16)b.w};
}

#define BM 128
#define BN 128
#define BK 32

// ---------------- generic GEMM (R3, unchanged core) ----------------
// LDS tile: unpadded [128 rows][32 f16], 16B chunks XOR-swizzled.

template <bool AF16, bool BF16, bool TRANSV, bool OUTF32>
__global__ __launch_bounds__(256) void gemm_bt(const void* __restrict__ Av,
                                               const void* __restrict__ Bv,
                                               const float* __restrict__ bias,
                                               void* __restrict__ Yv,
                                               int M, int N, int K) {
  __shared__ __align__(16) _Float16 sA[BM * BK];
  __shared__ __align__(16) _Float16 sB[BN * BK];

  const int t = threadIdx.x, lane = t & 63, wid = t >> 6;
  const int m0 = blockIdx.x * BM, n0 = blockIdx.y * BN;
  const int wm = (wid >> 1) * 64, wn = (wid & 1) * 64;
  const int lrow = lane & 15, g = lane >> 4;

  f32x4 acc[4][4] = {};

  const int arow = 16 * wid + (lane >> 2);
  const int gq = (lane & 3) ^ ((lane >> 3) & 3);
  _Float16* lA1 = sA + wid * 512;
  _Float16* lA2 = sA + 2048 + wid * 512;
  _Float16* lB1 = sB + wid * 512;
  _Float16* lB2 = sB + 2048 + wid * 512;

  const int mrow = t >> 1, mhalf = t & 1;
  const int mm = (mrow >> 1) & 3;
  const int ch_lo = mrow * 4 + ((2 * mhalf) ^ mm);
  const int ch_hi = ch_lo ^ 1;

  const _Float16* pA16a = nullptr; const _Float16* pA16b = nullptr;
  const float* pA32 = nullptr;
  if constexpr (AF16) {
    const _Float16* A = (const _Float16*)Av;
    pA16a = A + (size_t)(m0 + arow) * K + gq * 8;
    pA16b = A + (size_t)(m0 + 64 + arow) * K + gq * 8;
  } else {
    pA32 = (const float*)Av + (size_t)(m0 + mrow) * K + mhalf * 16;
  }
  const _Float16* pB16a = nullptr; const _Float16* pB16b = nullptr;
  const float* pB32 = nullptr;
  if constexpr (BF16) {
    const _Float16* B = (const _Float16*)Bv;
    pB16a = B + (size_t)(n0 + arow) * K + gq * 8;
    pB16b = B + (size_t)(n0 + 64 + arow) * K + gq * 8;
  } else {
    pB32 = (const float*)Bv + (size_t)(n0 + mrow) * K + mhalf * 16;
  }

  const int xr = g ^ ((lrow >> 1) & 3);

  for (int k0 = 0; k0 < K; k0 += BK) {
    float4 av[4], bv4[4];
    if constexpr (!AF16) {
      const float4* p = (const float4*)(pA32 + k0);
      av[0] = p[0]; av[1] = p[1]; av[2] = p[2]; av[3] = p[3];
    }
    if constexpr (!BF16) {
      const float4* p = (const float4*)(pB32 + k0);
      bv4[0] = p[0]; bv4[1] = p[1]; bv4[2] = p[2]; bv4[3] = p[3];
    }
    __syncthreads();
    if constexpr (AF16) {
      gld_lds16(pA16a + k0, lA1);
      gld_lds16(pA16b + k0, lA2);
    } else {
      *(f16x8*)(sA + ch_lo * 8) = cvt8(av[0], av[1]);
      *(f16x8*)(sA + ch_hi * 8) = cvt8(av[2], av[3]);
    }
    if constexpr (BF16) {
      gld_lds16(pB16a + k0, lB1);
      gld_lds16(pB16b + k0, lB2);
    } else {
      *(f16x8*)(sB + ch_lo * 8) = cvt8(bv4[0], bv4[1]);
      *(f16x8*)(sB + ch_hi * 8) = cvt8(bv4[2], bv4[3]);
    }
    __syncthreads();

    f16x8 af[4], bf[4];
#pragma unroll
    for (int i = 0; i < 4; i++)
      af[i] = *(const f16x8*)(sA + (wm + i * 16 + lrow) * 32 + xr * 8);
#pragma unroll
    for (int j = 0; j < 4; j++)
      bf[j] = *(const f16x8*)(sB + (wn + j * 16 + lrow) * 32 + xr * 8);
#pragma unroll
    for (int i = 0; i < 4; i++)
#pragma unroll
      for (int j = 0; j < 4; j++)
        acc[i][j] = __builtin_amdgcn_mfma_f32_16x16x32_f16(af[i], bf[j], acc[i][j], 0, 0, 0);
  }

  const int orow = g * 4, ocol = lrow;
#pragma unroll
  for (int j = 0; j < 4; j++) {
    const int col = n0 + wn + j * 16 + ocol;
    const float bv = bias[col];
#pragma unroll
    for (int i = 0; i < 4; i++) {
      const int row = m0 + wm + i * 16 + orow;
      if constexpr (TRANSV) {
        // V^T: [b][h][dh][s'], s' = s with bits 2<->3 swapped (PV A-frag perm)
        _Float16* VT = (_Float16*)Yv;
        int s = row & 2047;
        int sp = (s & ~12) | ((s & 4) << 1) | ((s & 8) >> 1);
        _Float16* dst = VT + (((size_t)(row >> 11) * 16 + (col >> 6)) * 64 + (col & 63)) * 2048 + sp;
        f16x4 v = {(_Float16)(acc[i][j][0] + bv), (_Float16)(acc[i][j][1] + bv),
                   (_Float16)(acc[i][j][2] + bv), (_Float16)(acc[i][j][3] + bv)};
        *(f16x4*)dst = v;
      } else if constexpr (OUTF32) {
        float* Y = (float*)Yv;
#pragma unroll
        for (int r = 0; r < 4; r++) Y[(size_t)(row + r) * N + col] = acc[i][j][r] + bv;
      } else {
        _Float16* Y = (_Float16*)Yv;
#pragma unroll
        for (int r = 0; r < 4; r++) Y[(size_t)(row + r) * N + col] = (_Float16)(acc[i][j][r] + bv);
      }
    }
  }
}

// ---------------- fused QKV projection: N=3072, all-f16 ----------------
// grid (24, 64): x = n-block (fastest -> XCD round-robin shares A tile), y = m.
__global__ __launch_bounds__(256) void qkv_gemm(const _Float16* __restrict__ Xq,
                                                const _Float16* __restrict__ Xk,
                                                const _Float16* __restrict__ Xv,
                                                const _Float16* __restrict__ W,  // [3072][1024]
                                                const float* __restrict__ bq,
                                                const float* __restrict__ bk,
                                                const float* __restrict__ bv,
                                                _Float16* __restrict__ Qo,
                                                _Float16* __restrict__ Ko,
                                                _Float16* __restrict__ VT) {
  __shared__ __align__(16) _Float16 sA[BM * BK];
  __shared__ __align__(16) _Float16 sB[BN * BK];

  const int t = threadIdx.x, lane = t & 63, wid = t >> 6;
  const int n0g = blockIdx.x * BN, m0 = blockIdx.y * BM;
  const int seg = blockIdx.x >> 3, n0 = n0g & 1023;
  const _Float16* A = (seg == 0) ? Xq : (seg == 1) ? Xk : Xv;
  const float* bias = (seg == 0) ? bq : (seg == 1) ? bk : bv;
  const int K = 1024;

  const int wm = (wid >> 1) * 64, wn = (wid & 1) * 64;
  const int lrow = lane & 15, g = lane >> 4;

  f32x4 acc[4][4] = {};

  const int arow = 16 * wid + (lane >> 2);
  const int gq = (lane & 3) ^ ((lane >> 3) & 3);
  _Float16* lA1 = sA + wid * 512;
  _Float16* lA2 = sA + 2048 + wid * 512;
  _Float16* lB1 = sB + wid * 512;
  _Float16* lB2 = sB + 2048 + wid * 512;

  const _Float16* pA16a = A + (size_t)(m0 + arow) * K + gq * 8;
  const _Float16* pA16b = A + (size_t)(m0 + 64 + arow) * K + gq * 8;
  const _Float16* pB16a = W + (size_t)(n0g + arow) * K + gq * 8;
  const _Float16* pB16b = W + (size_t)(n0g + 64 + arow) * K + gq * 8;

  const int xr = g ^ ((lrow >> 1) & 3);

  for (int k0 = 0; k0 < K; k0 += BK) {
    __syncthreads();
    gld_lds16(pA16a + k0, lA1);
    gld_lds16(pA16b + k0, lA2);
    gld_lds16(pB16a + k0, lB1);
    gld_lds16(pB16b + k0, lB2);
    __syncthreads();

    f16x8 af[4], bf[4];
#pragma unroll
    for (int i = 0; i < 4; i++)
      af[i] = *(const f16x8*)(sA + (wm + i * 16 + lrow) * 32 + xr * 8);
#pragma unroll
    for (int j = 0; j < 4; j++)
      bf[j] = *(const f16x8*)(sB + (wn + j * 16 + lrow) * 32 + xr * 8);
#pragma unroll
    for (int i = 0; i < 4; i++)
#pragma unroll
      for (int j = 0; j < 4; j++)
        acc[i][j] = __builtin_amdgcn_mfma_f32_16x16x32_f16(af[i], bf[j], acc[i][j], 0, 0, 0);
  }

  const int orow = g * 4, ocol = lrow;
#pragma unroll
  for (int j = 0; j < 4; j++) {
    const int col = n0 + wn + j * 16 + ocol;
    const float bvv = bias[col];
#pragma unroll
    for (int i = 0; i < 4; i++) {
      const int row = m0 + wm + i * 16 + orow;
      if (seg == 2) {
        int s = row & 2047;
        int sp = (s & ~12) | ((s & 4) << 1) | ((s & 8) >> 1);
        _Float16* dst = VT + (((size_t)(row >> 11) * 16 + (col >> 6)) * 64 + (col & 63)) * 2048 + sp;
        f16x4 v = {(_Float16)(acc[i][j][0] + bvv), (_Float16)(acc[i][j][1] + bvv),
                   (_Float16)(acc[i][j][2] + bvv), (_Float16)(acc[i][j][3] + bvv)};
        *(f16x4*)dst = v;
      } else {
        _Float16* Y = (seg == 0) ? Qo : Ko;
#pragma unroll
        for (int r = 0; r < 4; r++) Y[(size_t)(row + r) * 1024 + col] = (_Float16)(acc[i][j][r] + bvv);
      }
    }
  }
}

// ---------------- attention: O = sigmoid(Q K^T / 8) V ----------------
// 256 q/block (4 waves x 64 q), 64-key tiles. P stays in registers:
// S^T via 32x32x16 (C-layout key=(reg&3)+8(reg>>2)+4g5, q=lane&31) feeds
// 32x32x8 B-operand (k=4g5+j, n=lane&31) chunk-by-chunk. A-operand = V^T
// fragments; global VT has s-bits2<->3 swapped so each pair-read is b128.
#define LDS_ROW 72

__global__ __launch_bounds__(256, 2) void attn_sig(const _Float16* __restrict__ Q,
                                                   const _Float16* __restrict__ K,
                                                   const _Float16* __restrict__ VT,
                                                   _Float16* __restrict__ O) {
  __shared__ __align__(16) _Float16 smem[256 * LDS_ROW];  // 36,864 B
  _Float16* sK = smem;                  // [64][72]
  _Float16* sVT = smem + 64 * LDS_ROW;  // [64][72]

  const int t = threadIdx.x, lane = t & 63, wid = t >> 6;
  const int l31 = lane & 31, g5 = lane >> 5;
  const int b = blockIdx.z, h = blockIdx.y, q0 = blockIdx.x * 256;
  const int qw = q0 + wid * 64;

  // Q fragments: B-operand of 32x32x16: n=q=lane&31, k=8*g5+j per 16-dh chunk
  f16x8 qf[2][4];
#pragma unroll
  for (int qt = 0; qt < 2; qt++) {
    const _Float16* qp = Q + (size_t)(b * 2048 + qw + qt * 32 + l31) * 1024 + h * 64;
#pragma unroll
    for (int dhc = 0; dhc < 4; dhc++) qf[qt][dhc] = *(const f16x8*)(qp + dhc * 16 + g5 * 8);
  }

  f32x16 oacc[2][2] = {};  // [qt][dht] : O^T[dh][q]

  const int srow = t >> 2, scol = (t & 3) * 16;
  const _Float16* kbase = K + ((size_t)(b * 2048) + srow) * 1024 + h * 64 + scol;
  const _Float16* vbase = VT + ((size_t)((b * 16 + h) * 64 + srow)) * 2048 + scol;

  for (int kt = 0; kt < 2048; kt += 64) {
    uint4 ka = *(const uint4*)(kbase + (size_t)kt * 1024);
    uint4 kb = *(const uint4*)(kbase + (size_t)kt * 1024 + 8);
    uint4 va = *(const uint4*)(vbase + kt);
    uint4 vb = *(const uint4*)(vbase + kt + 8);
    __syncthreads();
    *(uint4*)&sK[srow * LDS_ROW + scol] = ka;
    *(uint4*)&sK[srow * LDS_ROW + scol + 8] = kb;
    *(uint4*)&sVT[srow * LDS_ROW + scol] = va;
    *(uint4*)&sVT[srow * LDS_ROW + scol + 8] = vb;
    __syncthreads();

#pragma unroll
    for (int kt32 = 0; kt32 < 2; kt32++) {
      // K fragments: A-operand of 32x32x16: m=key=lane&31, k=8g5+j
      f16x8 kf[4];
#pragma unroll
      for (int dhc = 0; dhc < 4; dhc++)
        kf[dhc] = *(const f16x8*)&sK[(kt32 * 32 + l31) * LDS_ROW + dhc * 16 + g5 * 8];

      f16x4 p16[2][4];  // [qt][chunk]: P^T B-frags
#pragma unroll
      for (int qt = 0; qt < 2; qt++) {
        f32x16 sacc = {};
#pragma unroll
        for (int dhc = 0; dhc < 4; dhc++)
          sacc = __builtin_amdgcn_mfma_f32_32x32x16_f16(kf[dhc], qf[qt][dhc], sacc, 0, 0, 0);
#pragma unroll
        for (int c = 0; c < 4; c++) {
          f16x4 p4;
#pragma unroll
          for (int r = 0; r < 4; r++) {
            float e = __expf(sacc[4 * c + r] * -0.125f);
            p4[r] = (_Float16)__builtin_amdgcn_rcpf(1.0f + e);
          }
          p16[qt][c] = p4;
        }
      }

      // PV: chunk pairs tloc=0,1 cover local chunks {2tloc, 2tloc+1}
#pragma unroll
      for (int dht = 0; dht < 2; dht++)
#pragma unroll
        for (int tloc = 0; tloc < 2; tloc++) {
          f16x8 vfr = *(const f16x8*)&sVT[(dht * 32 + l31) * LDS_ROW + kt32 * 32 + tloc * 16 + g5 * 8];
          f16x4 vlo = __builtin_shufflevector(vfr, vfr, 0, 1, 2, 3);
          f16x4 vhi = __builtin_shufflevector(vfr, vfr, 4, 5, 6, 7);
#pragma unroll
          for (int qt = 0; qt < 2; qt++) {
            oacc[qt][dht] = __builtin_amdgcn_mfma_f32_32x32x8f16(vlo, p16[qt][tloc * 2 + 0],
                                                                 oacc[qt][dht], 0, 0, 0);
            oacc[qt][dht] = __builtin_amdgcn_mfma_f32_32x32x8f16(vhi, p16[qt][tloc * 2 + 1],
                                                                 oacc[qt][dht], 0, 0, 0);
          }
        }
    }
  }

  // epilogue: O^T regs -> LDS [q][dh] -> coalesced global
  __syncthreads();
  _Float16* ep = smem;  // [256][72]
#pragma unroll
  for (int qt = 0; qt < 2; qt++)
#pragma unroll
    for (int dht = 0; dht < 2; dht++)
#pragma unroll
      for (int c = 0; c < 4; c++) {
        f16x4 o4 = {(_Float16)oacc[qt][dht][4 * c + 0], (_Float16)oacc[qt][dht][4 * c + 1],
                    (_Float16)oacc[qt][dht][4 * c + 2], (_Float16)oacc[qt][dht][4 * c + 3]};
        *(f16x4*)&ep[(wid * 64 + qt * 32 + l31) * LDS_ROW + dht * 32 + c * 8 + g5 * 4] = o4;
      }
  __syncthreads();
#pragma unroll
  for (int i = 0; i < 8; i++) {
    const int q = i * 32 + (t >> 3), dhc = t & 7;
    f16x8 row = *(const f16x8*)&ep[q * LDS_ROW + dhc * 8];
    *(f16x8*)(O + (size_t)(b * 2048 + q0 + q) * 1024 + h * 64 + dhc * 8) = row;
  }
}

// ---------------- f32 -> f16 batch convert ----------------
struct CvtArgs {
  const float* src[7];
  _Float16* dst[7];
  int n[7];
  int cnt;
};

__global__ __launch_bounds__(256) void cvt_f32_f16(CvtArgs a) {
  const int ti = blockIdx.y;
  if (ti >= a.cnt) return;
  const int i = (blockIdx.x * 256 + threadIdx.x) * 8;
  if (i >= a.n[ti]) return;
  const float4* s = (const float4*)(a.src[ti] + i);
  float4 x = s[0], y = s[1];
  *(f16x8*)(a.dst[ti] + i) = cvt8(x, y);
}

extern "C" void kernel_launch(void* const* d_in, const int* in_sizes, int n_in,
                              void* d_out, int out_size, void* d_ws, size_t ws_size,
                              hipStream_t stream) {
  const float* query = (const float*)d_in[0];
  const float* key   = (const float*)d_in[1];
  const float* value = (const float*)d_in[2];
  const float* Wq = (const float*)d_in[3];
  const float* bq = (const float*)d_in[4];
  const float* Wk = (const float*)d_in[5];
  const float* bk = (const float*)d_in[6];
  const float* Wv = (const float*)d_in[7];
  const float* bv = (const float*)d_in[8];
  const float* Wo = (const float*)d_in[9];
  const float* bo = (const float*)d_in[10];
  float* out = (float*)d_out;

  const int D = 1024, M = 8192;
  const size_t MB = 1024 * 1024;
  char* ws = (char*)d_ws;
  dim3 bb(256), ga(8, 16, 4);

  if (ws_size >= 104 * MB) {
    _Float16* Xq = (_Float16*)(ws + 0 * MB);
    _Float16* Xk = (_Float16*)(ws + 16 * MB);
    _Float16* Xv = (_Float16*)(ws + 32 * MB);
    _Float16* Qp = (_Float16*)(ws + 48 * MB);
    _Float16* Kp = (_Float16*)(ws + 64 * MB);
    _Float16* VT = (_Float16*)(ws + 80 * MB);
    _Float16* Wf = (_Float16*)(ws + 96 * MB);  // [Wq;Wk;Wv;Wo] 4 x 1M f16
    _Float16* AO = Xq;                         // Xq dead after QKV projection
    CvtArgs ca{};
    ca.src[0] = query; ca.dst[0] = Xq; ca.n[0] = M * D;
    ca.src[1] = key;   ca.dst[1] = Xk; ca.n[1] = M * D;
    ca.src[2] = value; ca.dst[2] = Xv; ca.n[2] = M * D;
    ca.src[3] = Wq; ca.dst[3] = Wf + 0 * 1048576; ca.n[3] = D * D;
    ca.src[4] = Wk; ca.dst[4] = Wf + 1 * 1048576; ca.n[4] = D * D;
    ca.src[5] = Wv; ca.dst[5] = Wf + 2 * 1048576; ca.n[5] = D * D;
    ca.src[6] = Wo; ca.dst[6] = Wf + 3 * 1048576; ca.n[6] = D * D;
    ca.cnt = 7;
    cvt_f32_f16<<<dim3(4096, 7), bb, 0, stream>>>(ca);
    qkv_gemm<<<dim3(24, 64), bb, 0, stream>>>(Xq, Xk, Xv, Wf, bq, bk, bv, Qp, Kp, VT);
    attn_sig<<<ga, bb, 0, stream>>>(Qp, Kp, VT, AO);
    gemm_bt<true, true, false, true><<<dim3(64, 8), bb, 0, stream>>>(AO, Wf + 3 * 1048576, bo, out, M, D, D);
  } else {
    _Float16* Qp = (_Float16*)(ws + 0 * MB);
    _Float16* Kp = (_Float16*)(ws + 16 * MB);
    _Float16* VT = (_Float16*)(ws + 32 * MB);
    _Float16* AO = (_Float16*)(ws + 48 * MB);
    gemm_bt<false, false, false, false><<<dim3(64, 8), bb, 0, stream>>>(query, Wq, bq, Qp, M, D, D);
    gemm_bt<false, false, false, false><<<dim3(64, 8), bb, 0, stream>>>(key,   Wk, bk, Kp, M, D, D);
    gemm_bt<false, false, true,  false><<<dim3(64, 8), bb, 0, stream>>>(value, Wv, bv, VT, M, D, D);
    attn_sig<<<ga, bb, 0, stream>>>(Qp, Kp, VT, AO);
    gemm_bt<true, false, false, true><<<dim3(64, 8), bb, 0, stream>>>(AO, Wo, bo, out, M, D, D);
  }
}

// Round 6
// 377.345 us; speedup vs baseline: 1.4420x; 1.0056x over previous
//
#include <hip/hip_runtime.h>

// MHA sigmoid-attention, f32 interface, f16 MFMA internals.
// B=4, S=2048, D=1024, H=16, Dh=64.
// R5b: (R5 + compile fix for cvt_pkrtz's __fp16 vector return type)
//     attention PV upgraded 32x32x8 -> 32x32x16 (bit2<->3-swapped VT makes
//     sacc reg-octets exactly the B-operand); 128 q/block (4 blocks/CU);
//     software-pipelined K/V tile loads; -0.125 folded into Q frags.

typedef _Float16 f16x2 __attribute__((ext_vector_type(2)));
typedef _Float16 f16x4 __attribute__((ext_vector_type(4)));
typedef _Float16 f16x8 __attribute__((ext_vector_type(8)));
typedef __fp16   h16x2 __attribute__((ext_vector_type(2)));
typedef float    f32x4 __attribute__((ext_vector_type(4)));
typedef float    f32x16 __attribute__((ext_vector_type(16)));

typedef __attribute__((address_space(3))) void* lds_vp;
typedef const __attribute__((address_space(1))) void* gbl_vp;

__device__ __forceinline__ void gld_lds16(const void* g, void* l) {
  __builtin_amdgcn_global_load_lds((gbl_vp)g, (lds_vp)l, 16, 0, 0);
}

__device__ __forceinline__ f16x8 cvt8(float4 a, float4 b) {
  return (f16x8){(_Float16)a.x, (_Float16)a.y, (_Float16)a.z, (_Float16)a.w,
                 (_Float16)b.x, (_Float16)b.y, (_Float16)b.z, (_Float16)b.w};
}

__device__ __forceinline__ f16x2 pk2(float a, float b) {
  h16x2 r = __builtin_amdgcn_cvt_pkrtz(a, b);
  return __builtin_bit_cast(f16x2, r);
}

#define BM 128
#define BN 128
#define BK 32

// ---------------- generic GEMM (R3 core, unchanged) ----------------
template <bool AF16, bool BF16, bool TRANSV, bool OUTF32>
__global__ __launch_bounds__(256) void gemm_bt(const void* __restrict__ Av,
                                               const void* __restrict__ Bv,
                                               const float* __restrict__ bias,
                                               void* __restrict__ Yv,
                                               int M, int N, int K) {
  __shared__ __align__(16) _Float16 sA[BM * BK];
  __shared__ __align__(16) _Float16 sB[BN * BK];

  const int t = threadIdx.x, lane = t & 63, wid = t >> 6;
  const int m0 = blockIdx.x * BM, n0 = blockIdx.y * BN;
  const int wm = (wid >> 1) * 64, wn = (wid & 1) * 64;
  const int lrow = lane & 15, g = lane >> 4;

  f32x4 acc[4][4] = {};

  const int arow = 16 * wid + (lane >> 2);
  const int gq = (lane & 3) ^ ((lane >> 3) & 3);
  _Float16* lA1 = sA + wid * 512;
  _Float16* lA2 = sA + 2048 + wid * 512;
  _Float16* lB1 = sB + wid * 512;
  _Float16* lB2 = sB + 2048 + wid * 512;

  const int mrow = t >> 1, mhalf = t & 1;
  const int mm = (mrow >> 1) & 3;
  const int ch_lo = mrow * 4 + ((2 * mhalf) ^ mm);
  const int ch_hi = ch_lo ^ 1;

  const _Float16* pA16a = nullptr; const _Float16* pA16b = nullptr;
  const float* pA32 = nullptr;
  if constexpr (AF16) {
    const _Float16* A = (const _Float16*)Av;
    pA16a = A + (size_t)(m0 + arow) * K + gq * 8;
    pA16b = A + (size_t)(m0 + 64 + arow) * K + gq * 8;
  } else {
    pA32 = (const float*)Av + (size_t)(m0 + mrow) * K + mhalf * 16;
  }
  const _Float16* pB16a = nullptr; const _Float16* pB16b = nullptr;
  const float* pB32 = nullptr;
  if constexpr (BF16) {
    const _Float16* B = (const _Float16*)Bv;
    pB16a = B + (size_t)(n0 + arow) * K + gq * 8;
    pB16b = B + (size_t)(n0 + 64 + arow) * K + gq * 8;
  } else {
    pB32 = (const float*)Bv + (size_t)(n0 + mrow) * K + mhalf * 16;
  }

  const int xr = g ^ ((lrow >> 1) & 3);

  for (int k0 = 0; k0 < K; k0 += BK) {
    float4 av[4], bv4[4];
    if constexpr (!AF16) {
      const float4* p = (const float4*)(pA32 + k0);
      av[0] = p[0]; av[1] = p[1]; av[2] = p[2]; av[3] = p[3];
    }
    if constexpr (!BF16) {
      const float4* p = (const float4*)(pB32 + k0);
      bv4[0] = p[0]; bv4[1] = p[1]; bv4[2] = p[2]; bv4[3] = p[3];
    }
    __syncthreads();
    if constexpr (AF16) {
      gld_lds16(pA16a + k0, lA1);
      gld_lds16(pA16b + k0, lA2);
    } else {
      *(f16x8*)(sA + ch_lo * 8) = cvt8(av[0], av[1]);
      *(f16x8*)(sA + ch_hi * 8) = cvt8(av[2], av[3]);
    }
    if constexpr (BF16) {
      gld_lds16(pB16a + k0, lB1);
      gld_lds16(pB16b + k0, lB2);
    } else {
      *(f16x8*)(sB + ch_lo * 8) = cvt8(bv4[0], bv4[1]);
      *(f16x8*)(sB + ch_hi * 8) = cvt8(bv4[2], bv4[3]);
    }
    __syncthreads();

    f16x8 af[4], bf[4];
#pragma unroll
    for (int i = 0; i < 4; i++)
      af[i] = *(const f16x8*)(sA + (wm + i * 16 + lrow) * 32 + xr * 8);
#pragma unroll
    for (int j = 0; j < 4; j++)
      bf[j] = *(const f16x8*)(sB + (wn + j * 16 + lrow) * 32 + xr * 8);
#pragma unroll
    for (int i = 0; i < 4; i++)
#pragma unroll
      for (int j = 0; j < 4; j++)
        acc[i][j] = __builtin_amdgcn_mfma_f32_16x16x32_f16(af[i], bf[j], acc[i][j], 0, 0, 0);
  }

  const int orow = g * 4, ocol = lrow;
#pragma unroll
  for (int j = 0; j < 4; j++) {
    const int col = n0 + wn + j * 16 + ocol;
    const float bv = bias[col];
#pragma unroll
    for (int i = 0; i < 4; i++) {
      const int row = m0 + wm + i * 16 + orow;
      if constexpr (TRANSV) {
        _Float16* VT = (_Float16*)Yv;
        int s = row & 2047;
        int sp = (s & ~12) | ((s & 4) << 1) | ((s & 8) >> 1);
        _Float16* dst = VT + (((size_t)(row >> 11) * 16 + (col >> 6)) * 64 + (col & 63)) * 2048 + sp;
        f16x4 v = {(_Float16)(acc[i][j][0] + bv), (_Float16)(acc[i][j][1] + bv),
                   (_Float16)(acc[i][j][2] + bv), (_Float16)(acc[i][j][3] + bv)};
        *(f16x4*)dst = v;
      } else if constexpr (OUTF32) {
        float* Y = (float*)Yv;
#pragma unroll
        for (int r = 0; r < 4; r++) Y[(size_t)(row + r) * N + col] = acc[i][j][r] + bv;
      } else {
        _Float16* Y = (_Float16*)Yv;
#pragma unroll
        for (int r = 0; r < 4; r++) Y[(size_t)(row + r) * N + col] = (_Float16)(acc[i][j][r] + bv);
      }
    }
  }
}

// ---------------- fused QKV projection: N=3072, all-f16 ----------------
__global__ __launch_bounds__(256) void qkv_gemm(const _Float16* __restrict__ Xq,
                                                const _Float16* __restrict__ Xk,
                                                const _Float16* __restrict__ Xv,
                                                const _Float16* __restrict__ W,
                                                const float* __restrict__ bq,
                                                const float* __restrict__ bk,
                                                const float* __restrict__ bv,
                                                _Float16* __restrict__ Qo,
                                                _Float16* __restrict__ Ko,
                                                _Float16* __restrict__ VT) {
  __shared__ __align__(16) _Float16 sA[BM * BK];
  __shared__ __align__(16) _Float16 sB[BN * BK];

  const int t = threadIdx.x, lane = t & 63, wid = t >> 6;
  const int n0g = blockIdx.x * BN, m0 = blockIdx.y * BM;
  const int seg = blockIdx.x >> 3, n0 = n0g & 1023;
  const _Float16* A = (seg == 0) ? Xq : (seg == 1) ? Xk : Xv;
  const float* bias = (seg == 0) ? bq : (seg == 1) ? bk : bv;
  const int K = 1024;

  const int wm = (wid >> 1) * 64, wn = (wid & 1) * 64;
  const int lrow = lane & 15, g = lane >> 4;

  f32x4 acc[4][4] = {};

  const int arow = 16 * wid + (lane >> 2);
  const int gq = (lane & 3) ^ ((lane >> 3) & 3);
  _Float16* lA1 = sA + wid * 512;
  _Float16* lA2 = sA + 2048 + wid * 512;
  _Float16* lB1 = sB + wid * 512;
  _Float16* lB2 = sB + 2048 + wid * 512;

  const _Float16* pA16a = A + (size_t)(m0 + arow) * K + gq * 8;
  const _Float16* pA16b = A + (size_t)(m0 + 64 + arow) * K + gq * 8;
  const _Float16* pB16a = W + (size_t)(n0g + arow) * K + gq * 8;
  const _Float16* pB16b = W + (size_t)(n0g + 64 + arow) * K + gq * 8;

  const int xr = g ^ ((lrow >> 1) & 3);

  for (int k0 = 0; k0 < K; k0 += BK) {
    __syncthreads();
    gld_lds16(pA16a + k0, lA1);
    gld_lds16(pA16b + k0, lA2);
    gld_lds16(pB16a + k0, lB1);
    gld_lds16(pB16b + k0, lB2);
    __syncthreads();

    f16x8 af[4], bf[4];
#pragma unroll
    for (int i = 0; i < 4; i++)
      af[i] = *(const f16x8*)(sA + (wm + i * 16 + lrow) * 32 + xr * 8);
#pragma unroll
    for (int j = 0; j < 4; j++)
      bf[j] = *(const f16x8*)(sB + (wn + j * 16 + lrow) * 32 + xr * 8);
#pragma unroll
    for (int i = 0; i < 4; i++)
#pragma unroll
      for (int j = 0; j < 4; j++)
        acc[i][j] = __builtin_amdgcn_mfma_f32_16x16x32_f16(af[i], bf[j], acc[i][j], 0, 0, 0);
  }

  const int orow = g * 4, ocol = lrow;
#pragma unroll
  for (int j = 0; j < 4; j++) {
    const int col = n0 + wn + j * 16 + ocol;
    const float bvv = bias[col];
#pragma unroll
    for (int i = 0; i < 4; i++) {
      const int row = m0 + wm + i * 16 + orow;
      if (seg == 2) {
        int s = row & 2047;
        int sp = (s & ~12) | ((s & 4) << 1) | ((s & 8) >> 1);
        _Float16* dst = VT + (((size_t)(row >> 11) * 16 + (col >> 6)) * 64 + (col & 63)) * 2048 + sp;
        f16x4 v = {(_Float16)(acc[i][j][0] + bvv), (_Float16)(acc[i][j][1] + bvv),
                   (_Float16)(acc[i][j][2] + bvv), (_Float16)(acc[i][j][3] + bvv)};
        *(f16x4*)dst = v;
      } else {
        _Float16* Y = (seg == 0) ? Qo : Ko;
#pragma unroll
        for (int r = 0; r < 4; r++) Y[(size_t)(row + r) * 1024 + col] = (_Float16)(acc[i][j][r] + bvv);
      }
    }
  }
}

// ---------------- attention: O = sigmoid(Q K^T / 8) V ----------------
// 128 q/block, 4 waves x 32 q. S^T via 32x32x16; PV also 32x32x16:
// with VT's s-bit2<->3 swap, sacc regs [G*8..G*8+7] are exactly the
// B-operand (k=g5*8+j) of the PV MFMA on 16-key group G, and the A-operand
// is a contiguous b128 from sVT. Q frags pre-scaled by -0.125 (exact pow2).
#define LDS_ROW 72

__global__ __launch_bounds__(256, 4) void attn_sig(const _Float16* __restrict__ Q,
                                                   const _Float16* __restrict__ K,
                                                   const _Float16* __restrict__ VT,
                                                   _Float16* __restrict__ O) {
  __shared__ __align__(16) _Float16 smem[128 * LDS_ROW];  // 18,432 B
  _Float16* sK = smem;                  // [64][72]
  _Float16* sVT = smem + 64 * LDS_ROW;  // [64][72]

  const int t = threadIdx.x, lane = t & 63, wid = t >> 6;
  const int l31 = lane & 31, g5 = lane >> 5;
  const int b = blockIdx.z, h = blockIdx.y, q0 = blockIdx.x * 128;
  const int qw = q0 + wid * 32;

  // Q fragments: B-operand of 32x32x16 (n=q=l31, k=8g5+j), scaled by -1/8
  f16x8 qf[4];
  {
    const _Float16* qp = Q + (size_t)(b * 2048 + qw + l31) * 1024 + h * 64;
#pragma unroll
    for (int dhc = 0; dhc < 4; dhc++)
      qf[dhc] = *(const f16x8*)(qp + dhc * 16 + g5 * 8) * (_Float16)-0.125f;
  }

  f32x16 oacc[2] = {};  // [dht] : O^T[dh][q]

  const int srow = t >> 2, scol = (t & 3) * 16;
  const _Float16* kbase = K + ((size_t)(b * 2048) + srow) * 1024 + h * 64 + scol;
  const _Float16* vbase = VT + ((size_t)((b * 16 + h) * 64 + srow)) * 2048 + scol;

  // software pipeline: tile kt is in registers when the loop body starts
  uint4 ka = *(const uint4*)kbase;
  uint4 kb = *(const uint4*)(kbase + 8);
  uint4 va = *(const uint4*)vbase;
  uint4 vb = *(const uint4*)(vbase + 8);

  for (int kt = 0; kt < 2048; kt += 64) {
    __syncthreads();  // prev tile's LDS reads done
    *(uint4*)&sK[srow * LDS_ROW + scol] = ka;
    *(uint4*)&sK[srow * LDS_ROW + scol + 8] = kb;
    *(uint4*)&sVT[srow * LDS_ROW + scol] = va;
    *(uint4*)&sVT[srow * LDS_ROW + scol + 8] = vb;
    __syncthreads();

    const int kt2 = kt + 64;
    if (kt2 < 2048) {  // issue next tile's loads; latency hides behind compute
      ka = *(const uint4*)(kbase + (size_t)kt2 * 1024);
      kb = *(const uint4*)(kbase + (size_t)kt2 * 1024 + 8);
      va = *(const uint4*)(vbase + kt2);
      vb = *(const uint4*)(vbase + kt2 + 8);
    }

#pragma unroll
    for (int kt32 = 0; kt32 < 2; kt32++) {
      // K fragments: A-operand (m=key=l31, k=8g5+j)
      f16x8 kf[4];
#pragma unroll
      for (int dhc = 0; dhc < 4; dhc++)
        kf[dhc] = *(const f16x8*)&sK[(kt32 * 32 + l31) * LDS_ROW + dhc * 16 + g5 * 8];

      f32x16 sacc = {};
#pragma unroll
      for (int dhc = 0; dhc < 4; dhc++)
        sacc = __builtin_amdgcn_mfma_f32_32x32x16_f16(kf[dhc], qf[dhc], sacc, 0, 0, 0);

      // sigmoid (arg already includes -1/8): p = rcp(1 + e^s); pack pairs
      f16x8 pf[2];
#pragma unroll
      for (int G = 0; G < 2; G++) {
        union { f16x8 v; f16x2 h[4]; } u;
#pragma unroll
        for (int pr = 0; pr < 4; pr++) {
          float e0 = __expf(sacc[G * 8 + pr * 2 + 0]);
          float e1 = __expf(sacc[G * 8 + pr * 2 + 1]);
          u.h[pr] = pk2(__builtin_amdgcn_rcpf(1.0f + e0),
                        __builtin_amdgcn_rcpf(1.0f + e1));
        }
        pf[G] = u.v;
      }

      // PV: oacc[dht] += VT-frag * P-frag (32x32x16)
#pragma unroll
      for (int dht = 0; dht < 2; dht++)
#pragma unroll
        for (int G = 0; G < 2; G++) {
          f16x8 vf = *(const f16x8*)&sVT[(dht * 32 + l31) * LDS_ROW + kt32 * 32 + G * 16 + g5 * 8];
          oacc[dht] = __builtin_amdgcn_mfma_f32_32x32x16_f16(vf, pf[G], oacc[dht], 0, 0, 0);
        }
    }
  }

  // epilogue: O^T regs -> LDS [q][dh] -> coalesced global
  __syncthreads();
  _Float16* ep = smem;  // [128][72]
#pragma unroll
  for (int dht = 0; dht < 2; dht++)
#pragma unroll
    for (int c = 0; c < 4; c++) {
      f16x4 o4 = {(_Float16)oacc[dht][4 * c + 0], (_Float16)oacc[dht][4 * c + 1],
                  (_Float16)oacc[dht][4 * c + 2], (_Float16)oacc[dht][4 * c + 3]};
      // dh covered: 8c + 4g5 + (0..3) within dht*32 group
      *(f16x4*)&ep[(wid * 32 + l31) * LDS_ROW + dht * 32 + c * 8 + g5 * 4] = o4;
    }
  __syncthreads();
#pragma unroll
  for (int i = 0; i < 4; i++) {
    const int q = i * 32 + (t >> 3), dhc = t & 7;
    f16x8 row = *(const f16x8*)&ep[q * LDS_ROW + dhc * 8];
    *(f16x8*)(O + (size_t)(b * 2048 + q0 + q) * 1024 + h * 64 + dhc * 8) = row;
  }
}

// ---------------- f32 -> f16 batch convert ----------------
struct CvtArgs {
  const float* src[7];
  _Float16* dst[7];
  int n[7];
  int cnt;
};

__global__ __launch_bounds__(256) void cvt_f32_f16(CvtArgs a) {
  const int ti = blockIdx.y;
  if (ti >= a.cnt) return;
  const int i = (blockIdx.x * 256 + threadIdx.x) * 8;
  if (i >= a.n[ti]) return;
  const float4* s = (const float4*)(a.src[ti] + i);
  float4 x = s[0], y = s[1];
  *(f16x8*)(a.dst[ti] + i) = cvt8(x, y);
}

extern "C" void kernel_launch(void* const* d_in, const int* in_sizes, int n_in,
                              void* d_out, int out_size, void* d_ws, size_t ws_size,
                              hipStream_t stream) {
  const float* query = (const float*)d_in[0];
  const float* key   = (const float*)d_in[1];
  const float* value = (const float*)d_in[2];
  const float* Wq = (const float*)d_in[3];
  const float* bq = (const float*)d_in[4];
  const float* Wk = (const float*)d_in[5];
  const float* bk = (const float*)d_in[6];
  const float* Wv = (const float*)d_in[7];
  const float* bv = (const float*)d_in[8];
  const float* Wo = (const float*)d_in[9];
  const float* bo = (const float*)d_in[10];
  float* out = (float*)d_out;

  const int D = 1024, M = 8192;
  const size_t MB = 1024 * 1024;
  char* ws = (char*)d_ws;
  dim3 bb(256), ga(16, 16, 4);

  if (ws_size >= 104 * MB) {
    _Float16* Xq = (_Float16*)(ws + 0 * MB);
    _Float16* Xk = (_Float16*)(ws + 16 * MB);
    _Float16* Xv = (_Float16*)(ws + 32 * MB);
    _Float16* Qp = (_Float16*)(ws + 48 * MB);
    _Float16* Kp = (_Float16*)(ws + 64 * MB);
    _Float16* VT = (_Float16*)(ws + 80 * MB);
    _Float16* Wf = (_Float16*)(ws + 96 * MB);  // [Wq;Wk;Wv;Wo] 4 x 1M f16
    _Float16* AO = Xq;                         // Xq dead after QKV projection
    CvtArgs ca{};
    ca.src[0] = query; ca.dst[0] = Xq; ca.n[0] = M * D;
    ca.src[1] = key;   ca.dst[1] = Xk; ca.n[1] = M * D;
    ca.src[2] = value; ca.dst[2] = Xv; ca.n[2] = M * D;
    ca.src[3] = Wq; ca.dst[3] = Wf + 0 * 1048576; ca.n[3] = D * D;
    ca.src[4] = Wk; ca.dst[4] = Wf + 1 * 1048576; ca.n[4] = D * D;
    ca.src[5] = Wv; ca.dst[5] = Wf + 2 * 1048576; ca.n[5] = D * D;
    ca.src[6] = Wo; ca.dst[6] = Wf + 3 * 1048576; ca.n[6] = D * D;
    ca.cnt = 7;
    cvt_f32_f16<<<dim3(4096, 7), bb, 0, stream>>>(ca);
    qkv_gemm<<<dim3(24, 64), bb, 0, stream>>>(Xq, Xk, Xv, Wf, bq, bk, bv, Qp, Kp, VT);
    attn_sig<<<ga, bb, 0, stream>>>(Qp, Kp, VT, AO);
    gemm_bt<true, true, false, true><<<dim3(64, 8), bb, 0, stream>>>(AO, Wf + 3 * 1048576, bo, out, M, D, D);
  } else {
    _Float16* Qp = (_Float16*)(ws + 0 * MB);
    _Float16* Kp = (_Float16*)(ws + 16 * MB);
    _Float16* VT = (_Float16*)(ws + 32 * MB);
    _Float16* AO = (_Float16*)(ws + 48 * MB);
    gemm_bt<false, false, false, false><<<dim3(64, 8), bb, 0, stream>>>(query, Wq, bq, Qp, M, D, D);
    gemm_bt<false, false, false, false><<<dim3(64, 8), bb, 0, stream>>>(key,   Wk, bk, Kp, M, D, D);
    gemm_bt<false, false, true,  false><<<dim3(64, 8), bb, 0, stream>>>(value, Wv, bv, VT, M, D, D);
    attn_sig<<<ga, bb, 0, stream>>>(Qp, Kp, VT, AO);
    gemm_bt<true, false, false, true><<<dim3(64, 8), bb, 0, stream>>>(AO, Wo, bo, out, M, D, D);
  }
}